// Round 1
// 2007.056 us; speedup vs baseline: 1.0761x; 1.0761x over previous
//
#include <hip/hip_runtime.h>
#include <hip/hip_bf16.h>
#include <stdint.h>

// SparseMLP on MI355X. fp16 MFMA path with 256x256-tile phase-interleaved GEMM
// (T2 swizzle + T3/T4 counted-vmcnt + T5 setprio, BK=32 x 4 LDS buffers).
// Pre-passes convert x/W1/W2 to fp16; fallback fp32 path if workspace small.

typedef __attribute__((ext_vector_type(8))) _Float16 half8;
typedef __attribute__((ext_vector_type(4))) float f32x4;

__device__ __forceinline__ void gld_lds16(const void* g, void* l) {
    __builtin_amdgcn_global_load_lds(
        (const __attribute__((address_space(1))) unsigned int*)g,
        (__attribute__((address_space(3))) unsigned int*)l, 16, 0, 0);
}

// ---------------- zero inactive output blocks ----------------
__global__ __launch_bounds__(256) void zero_kernel(
    float* __restrict__ out, const int* __restrict__ nz, int nnz)
{
    const int OUTD = 4096;
    int b = blockIdx.x;  // 0..63
    bool active = false;
    for (int i = 0; i < nnz; ++i) active |= (nz[i] == b);
    if (active) return;
    float4* p = (float4*)(out + (size_t)b * 128 * OUTD);
    const int total = 128 * OUTD / 4;
    const float4 z = make_float4(0.f, 0.f, 0.f, 0.f);
    for (int i = threadIdx.x + blockIdx.y * 256; i < total; i += 256 * gridDim.y)
        p[i] = z;
}

// ---------------- convert+transpose W (KxN fp32) -> (NxK fp16) ----------------
__global__ __launch_bounds__(256) void convT_kernel(
    const float* __restrict__ src, _Float16* __restrict__ dst, int K, int N)
{
    __shared__ float t[64][65];
    const int nb = blockIdx.x * 64, kb = blockIdx.y * 64;
    const int tid = threadIdx.x;
    #pragma unroll
    for (int i = 0; i < 4; ++i) {
        int idx = tid + i * 256;
        int r = idx >> 4, c4 = (idx & 15) * 4;
        float4 v = *(const float4*)(src + (size_t)(kb + r) * N + nb + c4);
        t[r][c4 + 0] = v.x; t[r][c4 + 1] = v.y;
        t[r][c4 + 2] = v.z; t[r][c4 + 3] = v.w;
    }
    __syncthreads();
    #pragma unroll
    for (int i = 0; i < 2; ++i) {
        int idx = tid + i * 256;
        int rn = idx >> 3, c8 = (idx & 7) * 8;
        _Float16 tmp[8];
        #pragma unroll
        for (int j = 0; j < 8; ++j) tmp[j] = (_Float16)t[c8 + j][rn];
        *(uint4*)(dst + (size_t)(nb + rn) * K + kb + c8) = *(const uint4*)tmp;
    }
}

// ---------------- gather+convert x -> xg fp16 (4096 x 4096) ----------------
__global__ __launch_bounds__(256) void convx_kernel(
    const float* __restrict__ x, const int* __restrict__ nz, _Float16* __restrict__ xg)
{
    const int EMBED = 4096;
    int row = blockIdx.x;  // active row 0..4095
    int blk = nz[row >> 7];
    const float* src = x + ((size_t)blk * 128 + (row & 127)) * EMBED;
    _Float16* dst = xg + (size_t)row * EMBED;
    for (int i = threadIdx.x; i < EMBED / 4; i += 256) {
        float4 v = *(const float4*)(src + i * 4);
        _Float16 tmp[4] = {(_Float16)v.x, (_Float16)v.y, (_Float16)v.z, (_Float16)v.w};
        *(uint2*)(dst + i * 4) = *(const uint2*)tmp;
    }
}

// ================== 256x256-tile phase-interleaved f16 GEMM ==================
// A: M x K row-major (M = 4096), BT: N x K row-major, out: fp16 H or scattered
// fp32. 512 threads = 8 waves (2 M x 4 N), per-wave 128x64 output.
// BK=32, 4 LDS buffers (A+B = 128 KiB), prefetch t+2, counted vmcnt(4).
// LDS XOR swizzle: logical slot l of row r stored at physical l ^ ((r>>1)&3);
// gld_lds dest is LINEAR, the global source is inverse-permuted (rule #21).
template<int K, int N, bool SCATTER>
__global__ __launch_bounds__(512, 2) void gemm256_kernel(
    const _Float16* __restrict__ A,
    const _Float16* __restrict__ BT,
    const int* __restrict__ nz,
    void* __restrict__ outp)
{
    const int MTILES = 16;            // M = 4096 always
    const int NTILES = N / 256;
    const int nwg = MTILES * NTILES;  // 1024 or 256: % 8 == 0 -> bijective swz
    int bid = blockIdx.x;
    int swz = (bid & 7) * (nwg >> 3) + (bid >> 3);   // XCD-aware (T1)
    const int m0 = (swz % MTILES) * 256;
    const int n0 = (swz / MTILES) * 256;

    __shared__ __align__(16) _Float16 As[4][256 * 32];   // 64 KiB
    __shared__ __align__(16) _Float16 Bs[4][256 * 32];   // 64 KiB

    const int tid = threadIdx.x;
    const int lane = tid & 63;
    const int wid = tid >> 6;
    const int wr = wid >> 2;          // 0..1  (M half)
    const int wc = wid & 3;           // 0..3  (N quarter)
    const int fr = lane & 15, fq = lane >> 4;
    // read-side swizzled slot: row = 16*c + fr  =>  (row>>1)&3 == (fr>>1)&3
    const int slotsw = fq ^ ((fr >> 1) & 3);

    // staging: tile = 1024 x 16B segs; thread handles s0=tid, s1=tid+512.
    // LDS linear seg s = (row = s>>2, phys slot = s&3); fetch logical slot
    // (s&3) ^ ((row>>1)&3) so the read-side XOR sees logical data.
    const int s0 = tid, s1 = tid + 512;
    const int ar0 = s0 >> 2, al0 = (s0 & 3) ^ ((ar0 >> 1) & 3);
    const int ar1 = s1 >> 2, al1 = (s1 & 3) ^ ((ar1 >> 1) & 3);
    const _Float16* gA0 = A + (size_t)(m0 + ar0) * K + al0 * 8;
    const _Float16* gA1 = A + (size_t)(m0 + ar1) * K + al1 * 8;
    const _Float16* gB0 = BT + (size_t)(n0 + ar0) * K + al0 * 8;
    const _Float16* gB1 = BT + (size_t)(n0 + ar1) * K + al1 * 8;

    const int aOff = (wr * 128 + fr) * 32 + slotsw * 8;  // elems
    const int bOff = (wc * 64 + fr) * 32 + slotsw * 8;

    f32x4 acc[8][4];
    #pragma unroll
    for (int i = 0; i < 8; ++i)
        #pragma unroll
        for (int j = 0; j < 4; ++j) acc[i][j] = (f32x4)(0.f);

    const int NKT = K / 32;

    // prologue: stage K-tiles 0,1 (4 loads each), wait for tile 0 only
    #pragma unroll
    for (int t = 0; t < 2; ++t) {
        char* la = (char*)&As[t][0];
        char* lb = (char*)&Bs[t][0];
        gld_lds16(gA0 + t * 32, la + s0 * 16);
        gld_lds16(gA1 + t * 32, la + s1 * 16);
        gld_lds16(gB0 + t * 32, lb + s0 * 16);
        gld_lds16(gB1 + t * 32, lb + s1 * 16);
    }
    asm volatile("s_waitcnt vmcnt(4)" ::: "memory");
    __builtin_amdgcn_s_barrier();

    for (int t = 0; t < NKT; ++t) {
        const _Float16* as = &As[t & 3][0];
        const _Float16* bs = &Bs[t & 3][0];
        half8 afr[4], bfr[4];

        // ---- phase 0: quadrant (M-lo, all N), 12 ds_reads, prefetch A(t+2)
        #pragma unroll
        for (int i = 0; i < 4; ++i)
            afr[i] = *(const half8*)(as + aOff + i * 512);
        #pragma unroll
        for (int j = 0; j < 4; ++j)
            bfr[j] = *(const half8*)(bs + bOff + j * 512);
        if (t + 2 < NKT) {
            char* la = (char*)&As[(t + 2) & 3][0];
            gld_lds16(gA0 + (t + 2) * 32, la + s0 * 16);
            gld_lds16(gA1 + (t + 2) * 32, la + s1 * 16);
        }
        __builtin_amdgcn_s_barrier();
        asm volatile("s_waitcnt lgkmcnt(0)" ::: "memory");
        __builtin_amdgcn_sched_barrier(0);
        __builtin_amdgcn_s_setprio(1);
        #pragma unroll
        for (int i = 0; i < 4; ++i)
            #pragma unroll
            for (int j = 0; j < 4; ++j)
                acc[i][j] = __builtin_amdgcn_mfma_f32_16x16x32_f16(afr[i], bfr[j], acc[i][j], 0, 0, 0);
        __builtin_amdgcn_s_setprio(0);
        __builtin_amdgcn_s_barrier();

        // ---- phase 1: quadrant (M-hi, all N), reuse B frags, prefetch B(t+2)
        #pragma unroll
        for (int i = 0; i < 4; ++i)
            afr[i] = *(const half8*)(as + aOff + 2048 + i * 512);
        if (t + 2 < NKT) {
            char* lb = (char*)&Bs[(t + 2) & 3][0];
            gld_lds16(gB0 + (t + 2) * 32, lb + s0 * 16);
            gld_lds16(gB1 + (t + 2) * 32, lb + s1 * 16);
        }
        __builtin_amdgcn_s_barrier();
        asm volatile("s_waitcnt lgkmcnt(0)" ::: "memory");
        __builtin_amdgcn_sched_barrier(0);
        __builtin_amdgcn_s_setprio(1);
        #pragma unroll
        for (int i = 0; i < 4; ++i)
            #pragma unroll
            for (int j = 0; j < 4; ++j)
                acc[4 + i][j] = __builtin_amdgcn_mfma_f32_16x16x32_f16(afr[i], bfr[j], acc[4 + i][j], 0, 0, 0);
        __builtin_amdgcn_s_setprio(0);
        // K-tile boundary: t+1's loads must have landed in every wave before
        // any wave reads buf[(t+1)&3]. Counted wait: 4 loads (t+2's) stay in
        // flight across the barrier. Only the final boundary drains to 0.
        if (t == NKT - 2) { asm volatile("s_waitcnt vmcnt(0)" ::: "memory"); }
        else              { asm volatile("s_waitcnt vmcnt(4)" ::: "memory"); }
        __builtin_amdgcn_s_barrier();
    }

    // ---- epilogue: C layout col = fr, row = fq*4 + r (verified mapping) ----
    if (!SCATTER) {
        _Float16* H = (_Float16*)outp;
        #pragma unroll
        for (int idx = 0; idx < 8; ++idx) {
            int mbase = m0 + wr * 128 + (idx >> 2) * 64 + (idx & 3) * 16 + fq * 4;
            #pragma unroll
            for (int j = 0; j < 4; ++j) {
                int n = n0 + wc * 64 + j * 16 + fr;
                #pragma unroll
                for (int r = 0; r < 4; ++r)
                    H[(size_t)(mbase + r) * N + n] = (_Float16)acc[idx][j][r];
            }
        }
    } else {
        float* out = (float*)outp;
        const int nzA = nz[m0 >> 7];
        const int nzB = nz[(m0 >> 7) + 1];
        const int blk = wr ? nzB : nzA;   // wr=0 -> rows 0..127, wr=1 -> 128..255
        #pragma unroll
        for (int idx = 0; idx < 8; ++idx) {
            int lm = (idx >> 2) * 64 + (idx & 3) * 16 + fq * 4;  // 0..127 in block
            #pragma unroll
            for (int j = 0; j < 4; ++j) {
                int n = n0 + wc * 64 + j * 16 + fr;
                #pragma unroll
                for (int r = 0; r < 4; ++r)
                    out[((size_t)blk * 128 + lm + r) * N + n] = acc[idx][j][r];
            }
        }
    }
}

// ================= fallback fp32 path (unchanged, passed) =================
#define TILE 128
#define BK16 16
#define LDSROW (TILE + 4)

__device__ inline unsigned short f2bf(float f) {
    unsigned int u = __float_as_uint(f);
    return (unsigned short)((u + 0x7FFFu + ((u >> 16) & 1u)) >> 16);
}

__global__ __launch_bounds__(256, 4) void gemm1_fp32_kernel(
    const float* __restrict__ x, const float* __restrict__ w1,
    const int* __restrict__ nz, unsigned short* __restrict__ h)
{
    const int EMBED = 4096, HIDDEN = 16384;
    __shared__ float As[BK16][LDSROW];
    __shared__ float Bs[BK16][LDSROW];
    const int by = blockIdx.x, bx = blockIdx.y;
    const int t = threadIdx.x, tx = t & 15, ty = t >> 4;
    const int blk = nz[by];
    const float* xsrc = x + (size_t)blk * 128 * EMBED;
    const int n0 = bx * TILE;
    float acc[8][8];
    #pragma unroll
    for (int i = 0; i < 8; ++i)
        #pragma unroll
        for (int j = 0; j < 8; ++j) acc[i][j] = 0.f;
    for (int k0 = 0; k0 < EMBED; k0 += BK16) {
        #pragma unroll
        for (int i = 0; i < 2; ++i) {
            int idx = t + i * 256, row = idx >> 2, kc = (idx & 3) << 2;
            const float4 v = *(const float4*)(xsrc + (size_t)row * EMBED + k0 + kc);
            As[kc][row] = v.x; As[kc + 1][row] = v.y; As[kc + 2][row] = v.z; As[kc + 3][row] = v.w;
        }
        #pragma unroll
        for (int i = 0; i < 2; ++i) {
            int idx = t + i * 256, kr = idx >> 5, nc = (idx & 31) << 2;
            *(float4*)&Bs[kr][nc] = *(const float4*)(w1 + (size_t)(k0 + kr) * HIDDEN + n0 + nc);
        }
        __syncthreads();
        #pragma unroll
        for (int kk = 0; kk < BK16; ++kk) {
            float a[8], b[8];
            *(float4*)&a[0] = *(const float4*)&As[kk][ty * 8];
            *(float4*)&a[4] = *(const float4*)&As[kk][ty * 8 + 4];
            *(float4*)&b[0] = *(const float4*)&Bs[kk][tx * 8];
            *(float4*)&b[4] = *(const float4*)&Bs[kk][tx * 8 + 4];
            #pragma unroll
            for (int i = 0; i < 8; ++i)
                #pragma unroll
                for (int j = 0; j < 8; ++j) acc[i][j] = fmaf(a[i], b[j], acc[i][j]);
        }
        __syncthreads();
    }
    #pragma unroll
    for (int i = 0; i < 8; ++i) {
        size_t row = (size_t)(by * TILE + ty * 8 + i);
        unsigned short tmp[8];
        #pragma unroll
        for (int j = 0; j < 8; ++j) tmp[j] = f2bf(acc[i][j]);
        *(uint4*)(h + row * HIDDEN + n0 + tx * 8) = *(const uint4*)tmp;
    }
}

__global__ __launch_bounds__(256, 4) void gemm2_fp32_kernel(
    const unsigned short* __restrict__ h, const float* __restrict__ w2,
    const int* __restrict__ nz, float* __restrict__ out)
{
    const int HIDDEN = 16384, OUTD = 4096;
    __shared__ float As[BK16][LDSROW];
    __shared__ float Bs[BK16][LDSROW];
    const int by = blockIdx.x, bx = blockIdx.y;
    const int t = threadIdx.x, tx = t & 15, ty = t >> 4;
    const unsigned short* hsrc = h + (size_t)by * TILE * HIDDEN;
    const int n0 = bx * TILE;
    float acc[8][8];
    #pragma unroll
    for (int i = 0; i < 8; ++i)
        #pragma unroll
        for (int j = 0; j < 8; ++j) acc[i][j] = 0.f;
    for (int k0 = 0; k0 < HIDDEN; k0 += BK16) {
        {
            int row = t >> 1, kc = (t & 1) << 3;
            uint4 v = *(const uint4*)(hsrc + (size_t)row * HIDDEN + k0 + kc);
            unsigned int w[4] = {v.x, v.y, v.z, v.w};
            #pragma unroll
            for (int q = 0; q < 4; ++q) {
                As[kc + 2 * q][row] = __uint_as_float(w[q] << 16);
                As[kc + 2 * q + 1][row] = __uint_as_float(w[q] & 0xFFFF0000u);
            }
        }
        #pragma unroll
        for (int i = 0; i < 2; ++i) {
            int idx = t + i * 256, kr = idx >> 5, nc = (idx & 31) << 2;
            *(float4*)&Bs[kr][nc] = *(const float4*)(w2 + (size_t)(k0 + kr) * OUTD + n0 + nc);
        }
        __syncthreads();
        #pragma unroll
        for (int kk = 0; kk < BK16; ++kk) {
            float a[8], b[8];
            *(float4*)&a[0] = *(const float4*)&As[kk][ty * 8];
            *(float4*)&a[4] = *(const float4*)&As[kk][ty * 8 + 4];
            *(float4*)&b[0] = *(const float4*)&Bs[kk][tx * 8];
            *(float4*)&b[4] = *(const float4*)&Bs[kk][tx * 8 + 4];
            #pragma unroll
            for (int i = 0; i < 8; ++i)
                #pragma unroll
                for (int j = 0; j < 8; ++j) acc[i][j] = fmaf(a[i], b[j], acc[i][j]);
        }
        __syncthreads();
    }
    const int blk = nz[by];
    #pragma unroll
    for (int i = 0; i < 8; ++i) {
        size_t orow = (size_t)blk * TILE + ty * 8 + i;
        float* dst = out + orow * OUTD + n0 + tx * 8;
        *(float4*)dst = make_float4(acc[i][0], acc[i][1], acc[i][2], acc[i][3]);
        *(float4*)(dst + 4) = make_float4(acc[i][4], acc[i][5], acc[i][6], acc[i][7]);
    }
}

extern "C" void kernel_launch(void* const* d_in, const int* in_sizes, int n_in,
                              void* d_out, int out_size, void* d_ws, size_t ws_size,
                              hipStream_t stream) {
    const float* x  = (const float*)d_in[0];
    const float* w1 = (const float*)d_in[1];
    const float* w2 = (const float*)d_in[2];
    const int* nz   = (const int*)d_in[3];
    const int nnz   = in_sizes[3];  // 32
    float* out = (float*)d_out;

    const int EMBED = 4096, HIDDEN = 16384, OUTD = 4096;
    const int rows = in_sizes[0] / EMBED;   // 8192
    const int nblocks = rows / 128;         // 64
    const int arows = nnz * 128;            // 4096 active rows

    const size_t MiB = 1024 * 1024;
    const size_t offXG = 0;                 // 32 MiB fp16
    const size_t offW1T = 32 * MiB;         // 128 MiB fp16 (16384 x 4096)
    const size_t offW2T = 160 * MiB;        // 128 MiB fp16 (4096 x 16384)
    const size_t offH = 288 * MiB;          // 128 MiB fp16 (4096 x 16384)
    const size_t need = 416 * MiB;

    zero_kernel<<<dim3(nblocks, 32), 256, 0, stream>>>(out, nz, nnz);

    if (ws_size >= need && arows == 4096) {
        _Float16* xg  = (_Float16*)((char*)d_ws + offXG);
        _Float16* w1t = (_Float16*)((char*)d_ws + offW1T);
        _Float16* w2t = (_Float16*)((char*)d_ws + offW2T);
        _Float16* h   = (_Float16*)((char*)d_ws + offH);
        convT_kernel<<<dim3(HIDDEN / 64, EMBED / 64), 256, 0, stream>>>(w1, w1t, EMBED, HIDDEN);
        convT_kernel<<<dim3(OUTD / 64, HIDDEN / 64), 256, 0, stream>>>(w2, w2t, HIDDEN, OUTD);
        convx_kernel<<<dim3(arows), 256, 0, stream>>>(x, nz, xg);
        gemm256_kernel<4096, 16384, false><<<dim3(16 * (16384 / 256)), 512, 0, stream>>>(xg, w1t, nullptr, h);
        gemm256_kernel<16384, 4096, true><<<dim3(16 * (4096 / 256)), 512, 0, stream>>>(h, w2t, nz, out);
    } else {
        unsigned short* h = (unsigned short*)d_ws;  // bf16 H (128 MiB)
        gemm1_fp32_kernel<<<dim3(nnz, HIDDEN / TILE), 256, 0, stream>>>(x, w1, nz, h);
        gemm2_fp32_kernel<<<dim3(nnz, OUTD / TILE), 256, 0, stream>>>(h, w2, nz, out);
    }
}